// Round 3
// baseline (2199.953 us; speedup 1.0000x reference)
//
#include <hip/hip_runtime.h>
#include <hip/hip_bf16.h>

using bf16 = __hip_bfloat16;
typedef __attribute__((ext_vector_type(4))) float f32x4;
typedef __attribute__((ext_vector_type(8))) short s16x8;

#define DEV static __device__ __forceinline__
DEV float bf2f(bf16 x){ return __bfloat162float(x); }
DEV bf16  f2bf(float x){ return __float2bfloat16(x); }
DEV float silu_(float x){ return x / (1.f + expf(-x)); }

// ------------------------------------------------------------------
// Generic tiled bf16 MFMA GEMM:  C = alpha * (A @ B^T) + bias
// A: bf16 rows (lda=K). FUSE: A-tile = silu(A)·A2 elementwise.
// B: f32 or bf16 rows (ldb=K). EXPERT: M_eff=counts[z], rowbase=offsets[z];
// GATHER: A row via rowlist. C offset: (z/zdiv)*c_so + (z%zdiv)*c_si
// (EXPERT: offsets[z]*ldc).
// ------------------------------------------------------------------
template<bool B_F32, bool EXPERT, bool GATHER, bool OUT_BF16, bool BIAS, bool FUSE>
__global__ __launch_bounds__(256) void gemm_kernel(
    const bf16* __restrict__ A, const bf16* __restrict__ A2,
    const void* __restrict__ Bv,
    const float* __restrict__ bias, void* __restrict__ C,
    int M, int N, int K,
    long a_zoff, long b_zoff,
    int zdiv, long c_so, long c_si, int ldc,
    float alpha,
    const int* __restrict__ rowlist, const int* __restrict__ offsets,
    const int* __restrict__ counts)
{
  __shared__ __align__(16) bf16 As[128][72];
  __shared__ __align__(16) bf16 Bs[128][72];
  const int z = blockIdx.z;
  const int m0 = blockIdx.y * 128, n0 = blockIdx.x * 128;
  int Meff = M; long rowbase = 0;
  if (EXPERT){ Meff = counts[z]; rowbase = offsets[z]; }
  if (m0 >= Meff) return;
  const bf16* Ab = A + (EXPERT ? 0 : z * a_zoff);
  long coff;
  if (EXPERT) coff = rowbase * (long)ldc;
  else        coff = (long)(z / zdiv) * c_so + (long)(z % zdiv) * c_si;

  const int tid = threadIdx.x;
  const int lane = tid & 63, wid = tid >> 6;
  const int wm = wid >> 1, wn = wid & 1;
  f32x4 acc[4][4] = {};

  for (int k0 = 0; k0 < K; k0 += 64){
    #pragma unroll
    for (int it = 0; it < 4; it++){
      int slot = tid + 256 * it;
      int row = slot >> 3, kc = (slot & 7) << 3;
      // ---- A tile ----
      long ar = 0; bool aval;
      if (EXPERT){
        int i = m0 + row;
        aval = i < Meff;
        if (aval) ar = GATHER ? (long)rowlist[rowbase + i] : (rowbase + i);
      } else {
        aval = (m0 + row) < Meff;
        ar = m0 + row;
      }
      uint4 av = make_uint4(0u,0u,0u,0u);
      if (aval){
        if (FUSE){
          uint4 gv = *(const uint4*)(Ab + ar * (long)K + k0 + kc);
          uint4 uv = *(const uint4*)(A2 + ar * (long)K + k0 + kc);
          union { bf16 h[8]; uint4 v; } ug, uu, rz;
          ug.v = gv; uu.v = uv;
          #pragma unroll
          for (int j = 0; j < 8; j++){
            float gg = bf2f(ug.h[j]);
            rz.h[j] = f2bf(silu_(gg) * bf2f(uu.h[j]));
          }
          av = rz.v;
        } else {
          av = *(const uint4*)(Ab + ar * (long)K + k0 + kc);
        }
      }
      *(uint4*)(&As[row][kc]) = av;
      // ---- B tile ----
      bool bval = (n0 + row) < N;
      if (B_F32){
        const float* Bp = (const float*)Bv + z * b_zoff + (long)(n0 + row) * K + k0 + kc;
        float4 b0 = make_float4(0,0,0,0), b1 = make_float4(0,0,0,0);
        if (bval){ b0 = *(const float4*)Bp; b1 = *(const float4*)(Bp + 4); }
        union { bf16 h[8]; uint4 v; } u;
        u.h[0]=f2bf(b0.x); u.h[1]=f2bf(b0.y); u.h[2]=f2bf(b0.z); u.h[3]=f2bf(b0.w);
        u.h[4]=f2bf(b1.x); u.h[5]=f2bf(b1.y); u.h[6]=f2bf(b1.z); u.h[7]=f2bf(b1.w);
        *(uint4*)(&Bs[row][kc]) = u.v;
      } else {
        const bf16* Bp = (const bf16*)Bv + z * b_zoff + (long)(n0 + row) * K + k0 + kc;
        uint4 bv2 = make_uint4(0u,0u,0u,0u);
        if (bval) bv2 = *(const uint4*)Bp;
        *(uint4*)(&Bs[row][kc]) = bv2;
      }
    }
    __syncthreads();
    #pragma unroll
    for (int ks = 0; ks < 2; ks++){
      const int r16 = lane & 15;
      const int kk = ks * 32 + ((lane >> 4) << 3);
      s16x8 af[4], bfr[4];
      #pragma unroll
      for (int mi = 0; mi < 4; mi++) af[mi]  = *(const s16x8*)(&As[wm*64 + mi*16 + r16][kk]);
      #pragma unroll
      for (int ni = 0; ni < 4; ni++) bfr[ni] = *(const s16x8*)(&Bs[wn*64 + ni*16 + r16][kk]);
      #pragma unroll
      for (int mi = 0; mi < 4; mi++)
        #pragma unroll
        for (int ni = 0; ni < 4; ni++)
          acc[mi][ni] = __builtin_amdgcn_mfma_f32_16x16x32_bf16(af[mi], bfr[ni], acc[mi][ni], 0, 0, 0);
    }
    __syncthreads();
  }
  // ---- epilogue ----
  #pragma unroll
  for (int mi = 0; mi < 4; mi++){
    #pragma unroll
    for (int ni = 0; ni < 4; ni++){
      int col = n0 + wn*64 + ni*16 + (lane & 15);
      if (col >= N) continue;
      float bv = BIAS ? bias[col] : 0.f;
      #pragma unroll
      for (int i = 0; i < 4; i++){
        int rr = m0 + wm*64 + mi*16 + ((lane >> 4) << 2) + i;
        if (rr >= Meff) continue;
        float v = acc[mi][ni][i] * alpha + bv;
        long cidx = coff + (long)rr * ldc + col;
        if (OUT_BF16) ((bf16*)C)[cidx] = f2bf(v);
        else          ((float*)C)[cidx] = v;
      }
    }
  }
}

// ---------------- modulation GEMV: out[b][j] = dot(silu(vec[b]), w[j]) + b[j] ----
__global__ __launch_bounds__(256) void mod_kernel(const float* __restrict__ vec,
    const float* __restrict__ w, const float* __restrict__ b, float* __restrict__ out){
  int bb = blockIdx.y;
  __shared__ float sv[768];
  for (int i = threadIdx.x; i < 768; i += 256){ float v = vec[bb*768 + i]; sv[i] = v * (1.f/(1.f+expf(-v))); }
  __syncthreads();
  int j = blockIdx.x * 256 + threadIdx.x;   // grid.x = 18 -> j < 4608 always
  const float* wr = w + (long)j * 768;
  float acc = 0.f;
  for (int k = 0; k < 768; k++) acc += sv[k] * wr[k];
  out[bb*4608 + j] = acc + b[j];
}

// ---------------- y = (1+c)*LN(x) + s  (bf16 out) --------------------------------
__global__ __launch_bounds__(256) void ln_mod_kernel(const float* __restrict__ x,
    const float* __restrict__ mod, int sOff, int cOff, bf16* __restrict__ y, int L){
  int t = blockIdx.x; int b = t / L;
  const float* xr = x + (long)t * 768;
  __shared__ float red[256];
  int tid = threadIdx.x;
  float v[3]; float s = 0.f;
  #pragma unroll
  for (int i = 0; i < 3; i++){ v[i] = xr[tid + 256*i]; s += v[i]; }
  red[tid] = s; __syncthreads();
  for (int o = 128; o; o >>= 1){ if (tid < o) red[tid] += red[tid+o]; __syncthreads(); }
  float mean = red[0] * (1.f/768.f); __syncthreads();
  float s2 = 0.f;
  #pragma unroll
  for (int i = 0; i < 3; i++){ float d = v[i]-mean; s2 += d*d; }
  red[tid] = s2; __syncthreads();
  for (int o = 128; o; o >>= 1){ if (tid < o) red[tid] += red[tid+o]; __syncthreads(); }
  float rs = rsqrtf(red[0] * (1.f/768.f) + 1e-6f);
  const float* mb = mod + (long)b * 4608;
  #pragma unroll
  for (int i = 0; i < 3; i++){
    int d = tid + 256*i;
    y[(long)t*768 + d] = f2bf((1.f + mb[cOff+d]) * ((v[i]-mean)*rs) + mb[sOff+d]);
  }
}

// ---- h = x + g1*proj ; y = (1+c2)*LN(h) + s2  (bf16 y + f32 yf) -----------------
__global__ __launch_bounds__(256) void resid_ln_mod_kernel(const float* __restrict__ x,
    const float* __restrict__ proj, const float* __restrict__ mod,
    float* __restrict__ h, bf16* __restrict__ y, float* __restrict__ yf, int L){
  int t = blockIdx.x; int b = t / L;
  const float* mb = mod + (long)b * 4608;
  const float* xr = x + (long)t * 768;
  const float* pr = proj + (long)t * 768;
  __shared__ float red[256];
  int tid = threadIdx.x;
  float v[3]; float s = 0.f;
  #pragma unroll
  for (int i = 0; i < 3; i++){
    int d = tid + 256*i;
    float hv = xr[d] + mb[2*768 + d] * pr[d];
    h[(long)t*768 + d] = hv;
    v[i] = hv; s += hv;
  }
  red[tid] = s; __syncthreads();
  for (int o = 128; o; o >>= 1){ if (tid < o) red[tid] += red[tid+o]; __syncthreads(); }
  float mean = red[0] * (1.f/768.f); __syncthreads();
  float s2 = 0.f;
  #pragma unroll
  for (int i = 0; i < 3; i++){ float d = v[i]-mean; s2 += d*d; }
  red[tid] = s2; __syncthreads();
  for (int o = 128; o; o >>= 1){ if (tid < o) red[tid] += red[tid+o]; __syncthreads(); }
  float rs = rsqrtf(red[0] * (1.f/768.f) + 1e-6f);
  #pragma unroll
  for (int i = 0; i < 3; i++){
    int d = tid + 256*i;
    float val = (1.f + mb[4*768+d]) * ((v[i]-mean)*rs) + mb[3*768+d];
    y[(long)t*768 + d] = f2bf(val);
    yf[(long)t*768 + d] = val;
  }
}

// ---- qkv (T x 2304 bf16) -> RMS-normed Q,K + V^T, concatenated seq layout -------
__global__ __launch_bounds__(256) void qkv_scatter_kernel(const bf16* __restrict__ qkv,
    const float* __restrict__ qs, const float* __restrict__ ks,
    bf16* __restrict__ Q, bf16* __restrict__ Kb, bf16* __restrict__ Vt,
    int T, int L, int seqoff){
  int u = blockIdx.x * 4 + (threadIdx.x >> 6);
  int lane = threadIdx.x & 63;
  if (u >= T * 12) return;
  int t = u / 12, hh = u % 12;
  int b = t / L, l = t % L;
  const bf16* row = qkv + (long)t * 2304;
  float q = bf2f(row[hh*64 + lane]);
  float k = bf2f(row[768 + hh*64 + lane]);
  float v = bf2f(row[1536 + hh*64 + lane]);
  float q2 = q*q, k2 = k*k;
  for (int o = 32; o; o >>= 1){ q2 += __shfl_xor(q2, o); k2 += __shfl_xor(k2, o); }
  q = q * rsqrtf(q2*(1.f/64.f) + 1e-6f) * qs[lane];
  k = k * rsqrtf(k2*(1.f/64.f) + 1e-6f) * ks[lane];
  int bh = b*12 + hh;
  int seq = seqoff + l;
  long base = (long)bh * 1280 * 64;
  Q [base + (long)seq*64 + lane] = f2bf(q);
  Kb[base + (long)seq*64 + lane] = f2bf(k);
  Vt[base + (long)lane*1280 + seq] = f2bf(v);
}

// ---- row softmax over 1280, f32 in, bf16 out -----------------------------------
__global__ __launch_bounds__(256) void softmax_kernel(const float* __restrict__ S, bf16* __restrict__ P){
  long r = blockIdx.x;
  const float* sr = S + r * 1280;
  __shared__ float buf[1280];
  __shared__ float red[256];
  int tid = threadIdx.x;
  float mx = -1e30f;
  for (int i = tid; i < 1280; i += 256){ float v = sr[i]; buf[i] = v; mx = fmaxf(mx, v); }
  red[tid] = mx; __syncthreads();
  for (int o = 128; o; o >>= 1){ if (tid < o) red[tid] = fmaxf(red[tid], red[tid+o]); __syncthreads(); }
  float m = red[0]; __syncthreads();
  float s = 0.f;
  for (int i = tid; i < 1280; i += 256){ float e = expf(buf[i] - m); buf[i] = e; s += e; }
  red[tid] = s; __syncthreads();
  for (int o = 128; o; o >>= 1){ if (tid < o) red[tid] += red[tid+o]; __syncthreads(); }
  float inv = 1.f / red[0];
  bf16* pr = P + r * 1280;
  for (int i = tid; i < 1280; i += 256) pr[i] = f2bf(buf[i] * inv);
}

// ---- router: softmax over 8 logits, top-2, atomic counts (f32 input) -----------
__global__ __launch_bounds__(256) void router_kernel(const float* __restrict__ x2,
    const float* __restrict__ gw, float* __restrict__ tkw, int* __restrict__ tki,
    int* __restrict__ counts, int T){
  int t = blockIdx.x * 4 + (threadIdx.x >> 6);
  int lane = threadIdx.x & 63;
  if (t >= T) return;
  const float* xr = x2 + (long)t * 768;
  float xs[12];
  #pragma unroll
  for (int i = 0; i < 12; i++) xs[i] = xr[lane + 64*i];
  float sc[8];
  #pragma unroll
  for (int e = 0; e < 8; e++){
    const float* gr = gw + e * 768;
    float p = 0.f;
    #pragma unroll
    for (int i = 0; i < 12; i++) p += xs[i] * gr[lane + 64*i];
    for (int o = 32; o; o >>= 1) p += __shfl_xor(p, o);
    sc[e] = p;
  }
  if (lane == 0){
    float m = sc[0];
    for (int e = 1; e < 8; e++) m = fmaxf(m, sc[e]);
    float s = 0.f;
    for (int e = 0; e < 8; e++){ sc[e] = expf(sc[e] - m); s += sc[e]; }
    float inv = 1.f / s;
    for (int e = 0; e < 8; e++) sc[e] *= inv;
    int i0 = 0;
    for (int e = 1; e < 8; e++) if (sc[e] > sc[i0]) i0 = e;
    int i1 = -1;
    for (int e = 0; e < 8; e++){ if (e == i0) continue; if (i1 < 0 || sc[e] > sc[i1]) i1 = e; }
    tkw[t*2] = sc[i0]; tkw[t*2+1] = sc[i1];
    tki[t*2] = i0;     tki[t*2+1] = i1;
    atomicAdd(&counts[i0], 1); atomicAdd(&counts[i1], 1);
  }
}

__global__ void zero_counts_kernel(int* a, int* b){
  int i = threadIdx.x; if (i < 8){ a[i] = 0; b[i] = 0; }
}

__global__ void offsets_kernel(const int* counts, int* offsets, int* cursor){
  if (threadIdx.x == 0){
    int o = 0;
    for (int e = 0; e < 8; e++){ offsets[e] = o; o += counts[e]; cursor[e] = 0; }
  }
}

__global__ __launch_bounds__(256) void scatter_kernel(const int* __restrict__ tki,
    const int* __restrict__ offsets, int* __restrict__ cursor,
    int* __restrict__ rows, int* __restrict__ tpos, int T){
  int idx = blockIdx.x * 256 + threadIdx.x;
  if (idx >= T * 2) return;
  int t = idx >> 1;
  int e = tki[idx];
  int pos = atomicAdd(&cursor[e], 1);
  int g = offsets[e] + pos;
  rows[g] = t;
  tpos[idx] = g;
}

// ---- out = f32( h + g2 * (w0*ye[p0] + w1*ye[p1] + ys) ) -------------------------
__global__ __launch_bounds__(256) void combine_kernel(const float* __restrict__ h,
    const float* __restrict__ mod, const float* __restrict__ tkw, const int* __restrict__ tpos,
    const float* __restrict__ ye, const float* __restrict__ ys, float* __restrict__ out, int L){
  int t = blockIdx.x; int b = t / L;
  const float* g2 = mod + (long)b * 4608 + 5*768;
  float w0 = tkw[t*2], w1 = tkw[t*2+1];
  long p0 = (long)tpos[t*2] * 768, p1 = (long)tpos[t*2+1] * 768;
  for (int d = threadIdx.x; d < 768; d += 256){
    float y = w0 * ye[p0+d] + w1 * ye[p1+d] + ys[(long)t*768 + d];
    out[(long)t*768 + d] = h[(long)t*768 + d] + g2[d] * y;
  }
}

// =================================================================================
extern "C" void kernel_launch(void* const* d_in, const int* in_sizes, int n_in,
                              void* d_out, int out_size, void* d_ws, size_t ws_size,
                              hipStream_t stream){
  (void)in_sizes; (void)n_in; (void)out_size; (void)ws_size;
  const float* img   = (const float*)d_in[0];
  const float* txt   = (const float*)d_in[1];
  const float* vec   = (const float*)d_in[2];
  const float* imw   = (const float*)d_in[3];
  const float* imb   = (const float*)d_in[4];
  const float* tmw   = (const float*)d_in[5];
  const float* tmb   = (const float*)d_in[6];
  const float* iqkvw = (const float*)d_in[7];
  const float* iqkvb = (const float*)d_in[8];
  const float* ipw   = (const float*)d_in[9];
  const float* ipb   = (const float*)d_in[10];
  const float* tqkvw = (const float*)d_in[11];
  const float* tqkvb = (const float*)d_in[12];
  const float* tpw   = (const float*)d_in[13];
  const float* tpb   = (const float*)d_in[14];
  const float* iqs   = (const float*)d_in[15];
  const float* iks   = (const float*)d_in[16];
  const float* tqs   = (const float*)d_in[17];
  const float* tks   = (const float*)d_in[18];
  const float* igw   = (const float*)d_in[19];
  const float* ieg   = (const float*)d_in[20];
  const float* ieu   = (const float*)d_in[21];
  const float* ied   = (const float*)d_in[22];
  const float* isg   = (const float*)d_in[23];
  const float* isu   = (const float*)d_in[24];
  const float* isd   = (const float*)d_in[25];
  const float* tgw   = (const float*)d_in[26];
  const float* teg   = (const float*)d_in[27];
  const float* teu   = (const float*)d_in[28];
  const float* ted   = (const float*)d_in[29];
  const float* tsg   = (const float*)d_in[30];
  const float* tsu   = (const float*)d_in[31];
  const float* tsd   = (const float*)d_in[32];
  float* out_img = (float*)d_out;                       // f32 output (reference dtype)
  float* out_txt = (float*)d_out + (long)2*1024*768;

  char* ws = (char*)d_ws;
  size_t off = 0;
  auto alloc = [&](size_t n)->char*{
    off = (off + 255) & ~(size_t)255;
    char* p = ws + off; off += n; return p;
  };
  // ---------------- persistent (~20 MB) ----------------
  float* mod_i  = (float*)alloc(2*4608*4);
  float* mod_t  = (float*)alloc(2*4608*4);
  float* h_i    = (float*)alloc((size_t)2048*768*4);
  float* h_t    = (float*)alloc((size_t)512*768*4);
  bf16*  x2_i   = (bf16*) alloc((size_t)2048*768*2);
  bf16*  x2_t   = (bf16*) alloc((size_t)512*768*2);
  float* x2f_i  = (float*)alloc((size_t)2048*768*4);
  float* x2f_t  = (float*)alloc((size_t)512*768*4);
  float* tkw_i  = (float*)alloc(2048*2*4);
  int*   tki_i  = (int*)  alloc(2048*2*4);
  int*   cnt_i  = (int*)  alloc(8*4);
  int*   ofs_i  = (int*)  alloc(8*4);
  int*   cur_i  = (int*)  alloc(8*4);
  int*   rows_i = (int*)  alloc(4096*4);
  int*   tpos_i = (int*)  alloc(4096*4);
  float* tkw_t  = (float*)alloc(512*2*4);
  int*   tki_t  = (int*)  alloc(512*2*4);
  int*   cnt_t  = (int*)  alloc(8*4);
  int*   ofs_t  = (int*)  alloc(8*4);
  int*   cur_t  = (int*)  alloc(8*4);
  int*   rows_t = (int*)  alloc(1024*4);
  int*   tpos_t = (int*)  alloc(1024*4);

  size_t arena = (off + 255) & ~(size_t)255;
  // ---------- phase A region1: live through all of attention (~23.6 MB) ----------
  off = arena;
  bf16*  Qb   = (bf16*)alloc((size_t)24*1280*64*2);
  bf16*  Kb   = (bf16*)alloc((size_t)24*1280*64*2);
  bf16*  Vt   = (bf16*)alloc((size_t)24*1280*64*2);
  bf16*  O    = (bf16*) alloc((size_t)2*1280*768*2);
  float* pj_i = (float*)alloc((size_t)2048*768*4);
  float* pj_t = (float*)alloc((size_t)512*768*4);
  size_t sub = (off + 255) & ~(size_t)255;
  // ---------- phase A region2a: xm/qr, dead after qkv_scatter (~15.7 MB) ---------
  bf16*  xm_i = (bf16*)alloc((size_t)2048*768*2);
  bf16*  xm_t = (bf16*)alloc((size_t)512*768*2);
  bf16*  qr_i = (bf16*)alloc((size_t)2048*2304*2);
  bf16*  qr_t = (bf16*)alloc((size_t)512*2304*2);
  // ---------- phase A region2b: chunked S/P (6 heads/chunk), overlays 2a (~59 MB)
  off = sub;
  float* S    = (float*)alloc((size_t)6*1280*1280*4);
  bf16*  P    = (bf16*) alloc((size_t)6*1280*1280*2);
  // ---------- phase B img (overlays all of phase A, ~82 MB) ----------------------
  off = arena;
  bf16*  g_i   = (bf16*) alloc((size_t)4096*3072*2);
  bf16*  u_i   = (bf16*) alloc((size_t)4096*3072*2);
  float* ye_i  = (float*)alloc((size_t)4096*768*4);
  bf16*  gs_i  = (bf16*) alloc((size_t)2048*1536*2);
  bf16*  us_i  = (bf16*) alloc((size_t)2048*1536*2);
  float* ys_i  = (float*)alloc((size_t)2048*768*4);
  // ---------- phase B txt (overlays phase B img, runs after combine_img) ---------
  off = arena;
  bf16*  g_t   = (bf16*) alloc((size_t)1024*3072*2);
  bf16*  u_t   = (bf16*) alloc((size_t)1024*3072*2);
  float* ye_t  = (float*)alloc((size_t)1024*768*4);
  bf16*  gs_t  = (bf16*) alloc((size_t)512*1536*2);
  bf16*  us_t  = (bf16*) alloc((size_t)512*1536*2);
  float* ys_t  = (float*)alloc((size_t)512*768*4);

  // ======================= launches =======================
  zero_counts_kernel<<<1, 64, 0, stream>>>(cnt_i, cnt_t);
  mod_kernel<<<dim3(18,2), 256, 0, stream>>>(vec, imw, imb, mod_i);
  mod_kernel<<<dim3(18,2), 256, 0, stream>>>(vec, tmw, tmb, mod_t);
  ln_mod_kernel<<<2048, 256, 0, stream>>>(img, mod_i, 0, 768, xm_i, 1024);
  ln_mod_kernel<<<512,  256, 0, stream>>>(txt, mod_t, 0, 768, xm_t, 256);
  // QKV GEMMs
  gemm_kernel<true,false,false,true,true,false><<<dim3(18,16,1), 256, 0, stream>>>(
      xm_i, nullptr, iqkvw, iqkvb, qr_i, 2048, 2304, 768, 0, 0, 1, 0, 0, 2304, 1.f,
      nullptr, nullptr, nullptr);
  gemm_kernel<true,false,false,true,true,false><<<dim3(18,4,1), 256, 0, stream>>>(
      xm_t, nullptr, tqkvw, tqkvb, qr_t, 512, 2304, 768, 0, 0, 1, 0, 0, 2304, 1.f,
      nullptr, nullptr, nullptr);
  qkv_scatter_kernel<<<6144, 256, 0, stream>>>(qr_i, iqs, iks, Qb, Kb, Vt, 2048, 1024, 256);
  qkv_scatter_kernel<<<1536, 256, 0, stream>>>(qr_t, tqs, tks, Qb, Kb, Vt, 512, 256, 0);
  // attention in 4 chunks of 6 heads (S/P reused per chunk)
  for (int c = 0; c < 4; c++){
    const bf16* Qc = Qb + (size_t)c * 6 * 1280 * 64;
    const bf16* Kc = Kb + (size_t)c * 6 * 1280 * 64;
    const bf16* Vc = Vt + (size_t)c * 6 * 1280 * 64;
    bf16* Oc = O + (size_t)(c >> 1) * 1280 * 768 + (size_t)(c & 1) * 6 * 64;
    gemm_kernel<false,false,false,false,false,false><<<dim3(10,10,6), 256, 0, stream>>>(
        Qc, nullptr, (const void*)Kc, nullptr, S, 1280, 1280, 64,
        (long)1280*64, (long)1280*64, 1, (long)1280*1280, 0, 1280, 0.125f,
        nullptr, nullptr, nullptr);
    softmax_kernel<<<6*1280, 256, 0, stream>>>(S, P);
    gemm_kernel<false,false,false,true,false,false><<<dim3(1,10,6), 256, 0, stream>>>(
        P, nullptr, (const void*)Vc, nullptr, Oc, 1280, 64, 1280,
        (long)1280*1280, (long)64*1280, 1, 64, 0, 768, 1.f,
        nullptr, nullptr, nullptr);
  }
  // proj GEMMs
  gemm_kernel<true,false,false,false,true,false><<<dim3(6,8,2), 256, 0, stream>>>(
      O + (long)256*768, nullptr, ipw, ipb, pj_i, 1024, 768, 768,
      (long)1280*768, 0, 1, (long)1024*768, 0, 768, 1.f,
      nullptr, nullptr, nullptr);
  gemm_kernel<true,false,false,false,true,false><<<dim3(6,2,2), 256, 0, stream>>>(
      O, nullptr, tpw, tpb, pj_t, 256, 768, 768,
      (long)1280*768, 0, 1, (long)256*768, 0, 768, 1.f,
      nullptr, nullptr, nullptr);
  resid_ln_mod_kernel<<<2048, 256, 0, stream>>>(img, pj_i, mod_i, h_i, x2_i, x2f_i, 1024);
  resid_ln_mod_kernel<<<512,  256, 0, stream>>>(txt, pj_t, mod_t, h_t, x2_t, x2f_t, 256);
  // routers (f32 inputs to match reference top-2 selection)
  router_kernel<<<512, 256, 0, stream>>>(x2f_i, igw, tkw_i, tki_i, cnt_i, 2048);
  router_kernel<<<128, 256, 0, stream>>>(x2f_t, tgw, tkw_t, tki_t, cnt_t, 512);
  offsets_kernel<<<1, 1, 0, stream>>>(cnt_i, ofs_i, cur_i);
  offsets_kernel<<<1, 1, 0, stream>>>(cnt_t, ofs_t, cur_t);
  scatter_kernel<<<16, 256, 0, stream>>>(tki_i, ofs_i, cur_i, rows_i, tpos_i, 2048);
  scatter_kernel<<<4,  256, 0, stream>>>(tki_t, ofs_t, cur_t, rows_t, tpos_t, 512);
  // ---- img MoE ----
  gemm_kernel<true,true,true,true,false,false><<<dim3(24,16,8), 256, 0, stream>>>(
      x2_i, nullptr, ieg, nullptr, g_i, 2048, 3072, 768, 0, (long)3072*768, 1, 0, 0, 3072, 1.f,
      rows_i, ofs_i, cnt_i);
  gemm_kernel<true,true,true,true,false,false><<<dim3(24,16,8), 256, 0, stream>>>(
      x2_i, nullptr, ieu, nullptr, u_i, 2048, 3072, 768, 0, (long)3072*768, 1, 0, 0, 3072, 1.f,
      rows_i, ofs_i, cnt_i);
  gemm_kernel<true,true,false,false,false,true><<<dim3(6,16,8), 256, 0, stream>>>(
      g_i, u_i, ied, nullptr, ye_i, 2048, 768, 3072, 0, (long)768*3072, 1, 0, 0, 768, 1.f,
      nullptr, ofs_i, cnt_i);
  gemm_kernel<true,false,false,true,false,false><<<dim3(12,16,1), 256, 0, stream>>>(
      x2_i, nullptr, isg, nullptr, gs_i, 2048, 1536, 768, 0, 0, 1, 0, 0, 1536, 1.f,
      nullptr, nullptr, nullptr);
  gemm_kernel<true,false,false,true,false,false><<<dim3(12,16,1), 256, 0, stream>>>(
      x2_i, nullptr, isu, nullptr, us_i, 2048, 1536, 768, 0, 0, 1, 0, 0, 1536, 1.f,
      nullptr, nullptr, nullptr);
  gemm_kernel<true,false,false,false,false,true><<<dim3(6,16,1), 256, 0, stream>>>(
      gs_i, us_i, isd, nullptr, ys_i, 2048, 768, 1536, 0, 0, 1, 0, 0, 768, 1.f,
      nullptr, nullptr, nullptr);
  combine_kernel<<<2048, 256, 0, stream>>>(h_i, mod_i, tkw_i, tpos_i, ye_i, ys_i, out_img, 1024);
  // ---- txt MoE (buffers overlay img MoE; strictly after combine_img) ----
  gemm_kernel<true,true,true,true,false,false><<<dim3(24,4,8), 256, 0, stream>>>(
      x2_t, nullptr, teg, nullptr, g_t, 512, 3072, 768, 0, (long)3072*768, 1, 0, 0, 3072, 1.f,
      rows_t, ofs_t, cnt_t);
  gemm_kernel<true,true,true,true,false,false><<<dim3(24,4,8), 256, 0, stream>>>(
      x2_t, nullptr, teu, nullptr, u_t, 512, 3072, 768, 0, (long)3072*768, 1, 0, 0, 3072, 1.f,
      rows_t, ofs_t, cnt_t);
  gemm_kernel<true,true,false,false,false,true><<<dim3(6,4,8), 256, 0, stream>>>(
      g_t, u_t, ted, nullptr, ye_t, 512, 768, 3072, 0, (long)768*3072, 1, 0, 0, 768, 1.f,
      nullptr, ofs_t, cnt_t);
  gemm_kernel<true,false,false,true,false,false><<<dim3(12,4,1), 256, 0, stream>>>(
      x2_t, nullptr, tsg, nullptr, gs_t, 512, 1536, 768, 0, 0, 1, 0, 0, 1536, 1.f,
      nullptr, nullptr, nullptr);
  gemm_kernel<true,false,false,true,false,false><<<dim3(12,4,1), 256, 0, stream>>>(
      x2_t, nullptr, tsu, nullptr, us_t, 512, 1536, 768, 0, 0, 1, 0, 0, 1536, 1.f,
      nullptr, nullptr, nullptr);
  gemm_kernel<true,false,false,false,false,true><<<dim3(6,4,1), 256, 0, stream>>>(
      gs_t, us_t, tsd, nullptr, ys_t, 512, 768, 1536, 0, 0, 1, 0, 0, 768, 1.f,
      nullptr, nullptr, nullptr);
  combine_kernel<<<512, 256, 0, stream>>>(h_t, mod_t, tkw_t, tpos_t, ye_t, ys_t, out_txt, 256);
}

// Round 4
// 1821.094 us; speedup vs baseline: 1.2080x; 1.2080x over previous
//
#include <hip/hip_runtime.h>
#include <hip/hip_bf16.h>

using bf16 = __hip_bfloat16;
typedef __attribute__((ext_vector_type(4))) float f32x4;
typedef __attribute__((ext_vector_type(8))) short s16x8;

#define DEV static __device__ __forceinline__
DEV float bf2f(bf16 x){ return __bfloat162float(x); }
DEV bf16  f2bf(float x){ return __float2bfloat16(x); }
DEV float silu_(float x){ return x / (1.f + expf(-x)); }

// ------------------------------------------------------------------
// Pipelined tiled bf16 MFMA GEMM:  C = alpha * (A @ B^T) (+ bias)
// A bf16 rows (lda=K). FUSE: A-tile = silu(A)*A2. B f32 or bf16 rows (ldb=K).
// EXPERT: Meff=counts[z], rowbase=offsets[z]; GATHER: A row via rowlist.
// OUT: 0 = f32 store, 1 = bf16 store, 2 = f32 atomicAdd (bias only split 0).
// ksplit: blockIdx.z = z*ksplit + split; K-range [split*K/ksplit, ...).
// Register-prefetch double buffering: global loads for tile t+1 issue before
// the MFMA phase of tile t.
// ------------------------------------------------------------------
template<bool B_F32, bool EXPERT, bool GATHER, int OUT, bool BIAS, bool FUSE>
__global__ __launch_bounds__(256) void gemm_kernel(
    const bf16* __restrict__ A, const bf16* __restrict__ A2,
    const void* __restrict__ Bv,
    const float* __restrict__ bias, void* __restrict__ C,
    int M, int N, int K,
    long a_zoff, long b_zoff,
    int zdiv, long c_so, long c_si, int ldc,
    float alpha, int ksplit,
    const int* __restrict__ rowlist, const int* __restrict__ offsets,
    const int* __restrict__ counts)
{
  __shared__ __align__(16) bf16 As[128][72];
  __shared__ __align__(16) bf16 Bs[128][72];
  const int zz = blockIdx.z;
  const int z = zz / ksplit, split = zz % ksplit;
  const int m0 = blockIdx.y * 128, n0 = blockIdx.x * 128;
  int Meff = M; long rowbase = 0;
  if (EXPERT){ Meff = counts[z]; rowbase = offsets[z]; }
  if (m0 >= Meff) return;
  const bf16* Ab = A + (EXPERT ? 0 : z * a_zoff);
  long coff;
  if (EXPERT) coff = rowbase * (long)ldc;
  else        coff = (long)(z / zdiv) * c_so + (long)(z % zdiv) * c_si;

  const int klen = K / ksplit;
  const int kbeg = split * klen;
  const int NT = klen >> 6;

  const int tid = threadIdx.x;
  const int lane = tid & 63, wid = tid >> 6;
  const int wm = wid >> 1, wn = wid & 1;

  // per-slot row setup (k-independent)
  const int rbase = tid >> 3;            // 0..31
  const int kc = (tid & 7) << 3;         // 0..56
  const bf16* ap[4]; const bf16* ap2[4];
  const bf16* bp[4]; const float* bpf[4];
  bool avalid[4], bvalid[4];
  #pragma unroll
  for (int it = 0; it < 4; it++){
    int row = rbase + 32 * it;
    long ar = 0;
    if (EXPERT){
      int i = m0 + row;
      avalid[it] = i < Meff;
      if (avalid[it]) ar = GATHER ? (long)rowlist[rowbase + i] : (rowbase + i);
    } else {
      avalid[it] = (m0 + row) < Meff;
      ar = m0 + row;
    }
    ap[it] = Ab + ar * (long)K + kbeg + kc;
    if (FUSE) ap2[it] = A2 + ar * (long)K + kbeg + kc;
    bvalid[it] = (n0 + row) < N;
    long br = bvalid[it] ? (long)(n0 + row) : 0;
    if (B_F32) bpf[it] = (const float*)Bv + z * b_zoff + br * K + kbeg + kc;
    else       bp[it]  = (const bf16*) Bv + z * b_zoff + br * K + kbeg + kc;
  }

  uint4 ra[4], ru[4], rb[4];
  float4 fb0[4], fb1[4];
  const uint4 zero4 = make_uint4(0u,0u,0u,0u);

  auto LOAD = [&](int koff){
    #pragma unroll
    for (int it = 0; it < 4; it++){
      ra[it] = avalid[it] ? *(const uint4*)(ap[it] + koff) : zero4;
      if (FUSE) ru[it] = avalid[it] ? *(const uint4*)(ap2[it] + koff) : zero4;
      if (B_F32){
        if (bvalid[it]){ fb0[it] = *(const float4*)(bpf[it] + koff);
                         fb1[it] = *(const float4*)(bpf[it] + koff + 4); }
        else { fb0[it] = make_float4(0,0,0,0); fb1[it] = make_float4(0,0,0,0); }
      } else {
        rb[it] = bvalid[it] ? *(const uint4*)(bp[it] + koff) : zero4;
      }
    }
  };
  auto STORE = [&](){
    #pragma unroll
    for (int it = 0; it < 4; it++){
      int row = rbase + 32 * it;
      uint4 av = ra[it];
      if (FUSE){
        union { bf16 h[8]; uint4 v; } g_, u_, r_;
        g_.v = ra[it]; u_.v = ru[it];
        #pragma unroll
        for (int j = 0; j < 8; j++)
          r_.h[j] = f2bf(silu_(bf2f(g_.h[j])) * bf2f(u_.h[j]));
        av = r_.v;
      }
      *(uint4*)(&As[row][kc]) = av;
      if (B_F32){
        union { bf16 h[8]; uint4 v; } u;
        u.h[0]=f2bf(fb0[it].x); u.h[1]=f2bf(fb0[it].y); u.h[2]=f2bf(fb0[it].z); u.h[3]=f2bf(fb0[it].w);
        u.h[4]=f2bf(fb1[it].x); u.h[5]=f2bf(fb1[it].y); u.h[6]=f2bf(fb1[it].z); u.h[7]=f2bf(fb1[it].w);
        *(uint4*)(&Bs[row][kc]) = u.v;
      } else {
        *(uint4*)(&Bs[row][kc]) = rb[it];
      }
    }
  };

  f32x4 acc[4][4] = {};
  LOAD(0);
  for (int t = 0; t < NT; t++){
    STORE();
    __syncthreads();
    if (t + 1 < NT) LOAD((t + 1) << 6);
    #pragma unroll
    for (int ks = 0; ks < 2; ks++){
      const int r16 = lane & 15;
      const int kk = ks * 32 + ((lane >> 4) << 3);
      s16x8 af[4], bfr[4];
      #pragma unroll
      for (int mi = 0; mi < 4; mi++) af[mi]  = *(const s16x8*)(&As[wm*64 + mi*16 + r16][kk]);
      #pragma unroll
      for (int ni = 0; ni < 4; ni++) bfr[ni] = *(const s16x8*)(&Bs[wn*64 + ni*16 + r16][kk]);
      #pragma unroll
      for (int mi = 0; mi < 4; mi++)
        #pragma unroll
        for (int ni = 0; ni < 4; ni++)
          acc[mi][ni] = __builtin_amdgcn_mfma_f32_16x16x32_bf16(af[mi], bfr[ni], acc[mi][ni], 0, 0, 0);
    }
    __syncthreads();
  }
  // ---- epilogue ----
  #pragma unroll
  for (int mi = 0; mi < 4; mi++){
    #pragma unroll
    for (int ni = 0; ni < 4; ni++){
      int col = n0 + wn*64 + ni*16 + (lane & 15);
      if (col >= N) continue;
      float bv = 0.f;
      if (BIAS){ if (OUT != 2 || split == 0) bv = bias[col]; }
      #pragma unroll
      for (int i = 0; i < 4; i++){
        int rr = m0 + wm*64 + mi*16 + ((lane >> 4) << 2) + i;
        if (rr >= Meff) continue;
        float v = acc[mi][ni][i] * alpha + bv;
        long cidx = coff + (long)rr * ldc + col;
        if (OUT == 1)      ((bf16*)C)[cidx] = f2bf(v);
        else if (OUT == 0) ((float*)C)[cidx] = v;
        else               atomicAdd(&((float*)C)[cidx], v);
      }
    }
  }
}

// ---- f32 -> bf16 convert (n % 8 == 0) ------------------------------------------
__global__ __launch_bounds__(256) void f2b_kernel(const float* __restrict__ in,
    bf16* __restrict__ out, long n){
  long i = ((long)blockIdx.x * 256 + threadIdx.x) * 8;
  if (i >= n) return;
  float4 a = *(const float4*)(in + i);
  float4 b = *(const float4*)(in + i + 4);
  union { bf16 h[8]; uint4 v; } u;
  u.h[0]=f2bf(a.x); u.h[1]=f2bf(a.y); u.h[2]=f2bf(a.z); u.h[3]=f2bf(a.w);
  u.h[4]=f2bf(b.x); u.h[5]=f2bf(b.y); u.h[6]=f2bf(b.z); u.h[7]=f2bf(b.w);
  *(uint4*)(out + i) = u.v;
}

// ---- zero f32 buffer (n % 4 == 0) ----------------------------------------------
__global__ __launch_bounds__(256) void zerof_kernel(float* __restrict__ p, long n){
  long i = ((long)blockIdx.x * 256 + threadIdx.x) * 4;
  if (i < n) *(float4*)(p + i) = make_float4(0,0,0,0);
}

// ---- modulation GEMV (wave-per-output, coalesced) ------------------------------
__global__ __launch_bounds__(256) void mod_kernel(const float* __restrict__ vec,
    const float* __restrict__ w, const float* __restrict__ b, float* __restrict__ out){
  int bb = blockIdx.y;
  __shared__ float sv[768];
  int tid = threadIdx.x;
  for (int i = tid; i < 768; i += 256){ float v = vec[bb*768 + i]; sv[i] = v/(1.f+expf(-v)); }
  __syncthreads();
  int w4 = tid >> 6, lane = tid & 63;
  int j0 = blockIdx.x * 8 + w4 * 2;       // grid.x = 576 -> j < 4608
  for (int jj = 0; jj < 2; jj++){
    int j = j0 + jj;
    const float* wr = w + (long)j * 768;
    float p = 0.f;
    #pragma unroll
    for (int i = 0; i < 12; i++) p += sv[lane + 64*i] * wr[lane + 64*i];
    for (int o = 32; o; o >>= 1) p += __shfl_xor(p, o);
    if (lane == 0) out[bb*4608 + j] = p + b[j];
  }
}

// ---------------- y = (1+c)*LN(x) + s  (bf16 out) --------------------------------
__global__ __launch_bounds__(256) void ln_mod_kernel(const float* __restrict__ x,
    const float* __restrict__ mod, int sOff, int cOff, bf16* __restrict__ y, int L){
  int t = blockIdx.x; int b = t / L;
  const float* xr = x + (long)t * 768;
  __shared__ float red[256];
  int tid = threadIdx.x;
  float v[3]; float s = 0.f;
  #pragma unroll
  for (int i = 0; i < 3; i++){ v[i] = xr[tid + 256*i]; s += v[i]; }
  red[tid] = s; __syncthreads();
  for (int o = 128; o; o >>= 1){ if (tid < o) red[tid] += red[tid+o]; __syncthreads(); }
  float mean = red[0] * (1.f/768.f); __syncthreads();
  float s2 = 0.f;
  #pragma unroll
  for (int i = 0; i < 3; i++){ float d = v[i]-mean; s2 += d*d; }
  red[tid] = s2; __syncthreads();
  for (int o = 128; o; o >>= 1){ if (tid < o) red[tid] += red[tid+o]; __syncthreads(); }
  float rs = rsqrtf(red[0] * (1.f/768.f) + 1e-6f);
  const float* mb = mod + (long)b * 4608;
  #pragma unroll
  for (int i = 0; i < 3; i++){
    int d = tid + 256*i;
    y[(long)t*768 + d] = f2bf((1.f + mb[cOff+d]) * ((v[i]-mean)*rs) + mb[sOff+d]);
  }
}

// ---- h = x + g1*proj ; y = (1+c2)*LN(h) + s2  (bf16 y + f32 yf) -----------------
__global__ __launch_bounds__(256) void resid_ln_mod_kernel(const float* __restrict__ x,
    const float* __restrict__ proj, const float* __restrict__ mod,
    float* __restrict__ h, bf16* __restrict__ y, float* __restrict__ yf, int L){
  int t = blockIdx.x; int b = t / L;
  const float* mb = mod + (long)b * 4608;
  const float* xr = x + (long)t * 768;
  const float* pr = proj + (long)t * 768;
  __shared__ float red[256];
  int tid = threadIdx.x;
  float v[3]; float s = 0.f;
  #pragma unroll
  for (int i = 0; i < 3; i++){
    int d = tid + 256*i;
    float hv = xr[d] + mb[2*768 + d] * pr[d];
    h[(long)t*768 + d] = hv;
    v[i] = hv; s += hv;
  }
  red[tid] = s; __syncthreads();
  for (int o = 128; o; o >>= 1){ if (tid < o) red[tid] += red[tid+o]; __syncthreads(); }
  float mean = red[0] * (1.f/768.f); __syncthreads();
  float s2 = 0.f;
  #pragma unroll
  for (int i = 0; i < 3; i++){ float d = v[i]-mean; s2 += d*d; }
  red[tid] = s2; __syncthreads();
  for (int o = 128; o; o >>= 1){ if (tid < o) red[tid] += red[tid+o]; __syncthreads(); }
  float rs = rsqrtf(red[0] * (1.f/768.f) + 1e-6f);
  #pragma unroll
  for (int i = 0; i < 3; i++){
    int d = tid + 256*i;
    float val = (1.f + mb[4*768+d]) * ((v[i]-mean)*rs) + mb[3*768+d];
    y[(long)t*768 + d] = f2bf(val);
    yf[(long)t*768 + d] = val;
  }
}

// ---- qkv rows -> RMS-normed Q,K + transposed V (coalesced via LDS) --------------
// grid: (L/64, B*12); block handles 64 seq x 64 d for one (b,h)
__global__ __launch_bounds__(256) void qkv_scatter_kernel(const bf16* __restrict__ qkv,
    const float* __restrict__ qs, const float* __restrict__ ks,
    bf16* __restrict__ Q, bf16* __restrict__ Kb, bf16* __restrict__ Vt,
    int L, int seqoff){
  __shared__ float vt[64][65];
  int bh = blockIdx.y;
  int b = bh / 12, hh = bh % 12;
  int st = blockIdx.x * 64;
  int w = threadIdx.x >> 6, lane = threadIdx.x & 63;
  float qsc = qs[lane], ksc = ks[lane];
  long qkvbase = (long)b * L * 2304;
  long outbase = (long)bh * 1280 * 64;
  #pragma unroll 4
  for (int i = 0; i < 16; i++){
    int r = w*16 + i;
    int t = st + r;
    const bf16* row = qkv + qkvbase + (long)t * 2304;
    float q = bf2f(row[hh*64 + lane]);
    float k = bf2f(row[768 + hh*64 + lane]);
    float v = bf2f(row[1536 + hh*64 + lane]);
    float q2 = q*q, k2 = k*k;
    for (int o = 32; o; o >>= 1){ q2 += __shfl_xor(q2, o); k2 += __shfl_xor(k2, o); }
    q = q * rsqrtf(q2*(1.f/64.f) + 1e-6f) * qsc;
    k = k * rsqrtf(k2*(1.f/64.f) + 1e-6f) * ksc;
    int seq = seqoff + t;
    Q [outbase + (long)seq*64 + lane] = f2bf(q);
    Kb[outbase + (long)seq*64 + lane] = f2bf(k);
    vt[r][lane] = v;
  }
  __syncthreads();
  #pragma unroll 4
  for (int i = 0; i < 16; i++){
    int d = w*16 + i;
    Vt[outbase + (long)d*1280 + seqoff + st + lane] = f2bf(vt[lane][d]);
  }
}

// ---- row softmax over 1280, f32 in, bf16 out -----------------------------------
__global__ __launch_bounds__(256) void softmax_kernel(const float* __restrict__ S, bf16* __restrict__ P){
  long r = blockIdx.x;
  const float* sr = S + r * 1280;
  __shared__ float buf[1280];
  __shared__ float red[256];
  int tid = threadIdx.x;
  float mx = -1e30f;
  for (int i = tid; i < 1280; i += 256){ float v = sr[i]; buf[i] = v; mx = fmaxf(mx, v); }
  red[tid] = mx; __syncthreads();
  for (int o = 128; o; o >>= 1){ if (tid < o) red[tid] = fmaxf(red[tid], red[tid+o]); __syncthreads(); }
  float m = red[0]; __syncthreads();
  float s = 0.f;
  for (int i = tid; i < 1280; i += 256){ float e = expf(buf[i] - m); buf[i] = e; s += e; }
  red[tid] = s; __syncthreads();
  for (int o = 128; o; o >>= 1){ if (tid < o) red[tid] += red[tid+o]; __syncthreads(); }
  float inv = 1.f / red[0];
  bf16* pr = P + r * 1280;
  for (int i = tid; i < 1280; i += 256) pr[i] = f2bf(buf[i] * inv);
}

// ---- router: softmax over 8 logits, top-2, atomic counts (f32 input) -----------
__global__ __launch_bounds__(256) void router_kernel(const float* __restrict__ x2,
    const float* __restrict__ gw, float* __restrict__ tkw, int* __restrict__ tki,
    int* __restrict__ counts, int T){
  int t = blockIdx.x * 4 + (threadIdx.x >> 6);
  int lane = threadIdx.x & 63;
  if (t >= T) return;
  const float* xr = x2 + (long)t * 768;
  float xs[12];
  #pragma unroll
  for (int i = 0; i < 12; i++) xs[i] = xr[lane + 64*i];
  float sc[8];
  #pragma unroll
  for (int e = 0; e < 8; e++){
    const float* gr = gw + e * 768;
    float p = 0.f;
    #pragma unroll
    for (int i = 0; i < 12; i++) p += xs[i] * gr[lane + 64*i];
    for (int o = 32; o; o >>= 1) p += __shfl_xor(p, o);
    sc[e] = p;
  }
  if (lane == 0){
    float m = sc[0];
    for (int e = 1; e < 8; e++) m = fmaxf(m, sc[e]);
    float s = 0.f;
    for (int e = 0; e < 8; e++){ sc[e] = expf(sc[e] - m); s += sc[e]; }
    float inv = 1.f / s;
    for (int e = 0; e < 8; e++) sc[e] *= inv;
    int i0 = 0;
    for (int e = 1; e < 8; e++) if (sc[e] > sc[i0]) i0 = e;
    int i1 = -1;
    for (int e = 0; e < 8; e++){ if (e == i0) continue; if (i1 < 0 || sc[e] > sc[i1]) i1 = e; }
    tkw[t*2] = sc[i0]; tkw[t*2+1] = sc[i1];
    tki[t*2] = i0;     tki[t*2+1] = i1;
    atomicAdd(&counts[i0], 1); atomicAdd(&counts[i1], 1);
  }
}

__global__ void zero_counts_kernel(int* a, int* b){
  int i = threadIdx.x; if (i < 8){ a[i] = 0; b[i] = 0; }
}

__global__ void offsets_kernel(const int* counts, int* offsets, int* cursor){
  if (threadIdx.x == 0){
    int o = 0;
    for (int e = 0; e < 8; e++){ offsets[e] = o; o += counts[e]; cursor[e] = 0; }
  }
}

__global__ __launch_bounds__(256) void scatter_kernel(const int* __restrict__ tki,
    const int* __restrict__ offsets, int* __restrict__ cursor,
    int* __restrict__ rows, int* __restrict__ tpos, int T){
  int idx = blockIdx.x * 256 + threadIdx.x;
  if (idx >= T * 2) return;
  int t = idx >> 1;
  int e = tki[idx];
  int pos = atomicAdd(&cursor[e], 1);
  int g = offsets[e] + pos;
  rows[g] = t;
  tpos[idx] = g;
}

// ---- out = f32( h + g2 * (w0*ye[p0] + w1*ye[p1] + ys) ) -------------------------
__global__ __launch_bounds__(256) void combine_kernel(const float* __restrict__ h,
    const float* __restrict__ mod, const float* __restrict__ tkw, const int* __restrict__ tpos,
    const float* __restrict__ ye, const float* __restrict__ ys, float* __restrict__ out, int L){
  int t = blockIdx.x; int b = t / L;
  const float* g2 = mod + (long)b * 4608 + 5*768;
  float w0 = tkw[t*2], w1 = tkw[t*2+1];
  long p0 = (long)tpos[t*2] * 768, p1 = (long)tpos[t*2+1] * 768;
  for (int d = threadIdx.x; d < 768; d += 256){
    float y = w0 * ye[p0+d] + w1 * ye[p1+d] + ys[(long)t*768 + d];
    out[(long)t*768 + d] = h[(long)t*768 + d] + g2[d] * y;
  }
}

// =================================================================================
struct Ctx {
  const float *img,*txt,*vec,*imw,*imb,*tmw,*tmb,*iqkvb,*tqkvb,*ipb,*tpb,
              *iqs,*iks,*tqs,*tks,*igw,*tgw;
  const void *iqkvw,*tqkvw,*ipw,*tpw,*ieg,*ieu,*ied,*isg,*isu,*isd,
             *teg,*teu,*ted,*tsg,*tsu,*tsd;   // f32 (tier B) or bf16 (tier A)
  float *out_img,*out_txt;
  float *mod_i,*mod_t,*h_i,*h_t,*x2f_i,*x2f_t,*tkw_i,*tkw_t;
  bf16  *x2_i,*x2_t;
  int *tki_i,*cnt_i,*ofs_i,*cur_i,*rows_i,*tpos_i;
  int *tki_t,*cnt_t,*ofs_t,*cur_t,*rows_t,*tpos_t;
  bf16 *Qb,*Kb,*Vt,*O,*xm_i,*xm_t,*qr_i,*qr_t,*P;
  float *S,*Of,*pj_i,*pj_t;
  bf16 *g_i,*u_i,*gs_i,*us_i,*g_t,*u_t,*gs_t,*us_t;
  float *ye_i,*ys_i,*ye_t,*ys_t;
};

template<bool W>   // W=true: weights pre-converted to bf16
static void seq(const Ctx& c, hipStream_t s){
  constexpr bool BF = !W;   // B_F32 flag for weight-consuming GEMMs
  zero_counts_kernel<<<1, 64, 0, s>>>(c.cnt_i, c.cnt_t);
  mod_kernel<<<dim3(576,2), 256, 0, s>>>(c.vec, c.imw, c.imb, c.mod_i);
  mod_kernel<<<dim3(576,2), 256, 0, s>>>(c.vec, c.tmw, c.tmb, c.mod_t);
  ln_mod_kernel<<<2048, 256, 0, s>>>(c.img, c.mod_i, 0, 768, c.xm_i, 1024);
  ln_mod_kernel<<<512,  256, 0, s>>>(c.txt, c.mod_t, 0, 768, c.xm_t, 256);
  // QKV GEMMs
  gemm_kernel<BF,false,false,1,true,false><<<dim3(18,16,1), 256, 0, s>>>(
      c.xm_i, nullptr, c.iqkvw, c.iqkvb, c.qr_i, 2048, 2304, 768, 0, 0,
      1, 0, 0, 2304, 1.f, 1, nullptr, nullptr, nullptr);
  gemm_kernel<BF,false,false,1,true,false><<<dim3(18,4,1), 256, 0, s>>>(
      c.xm_t, nullptr, c.tqkvw, c.tqkvb, c.qr_t, 512, 2304, 768, 0, 0,
      1, 0, 0, 2304, 1.f, 1, nullptr, nullptr, nullptr);
  qkv_scatter_kernel<<<dim3(16,24), 256, 0, s>>>(c.qr_i, c.iqs, c.iks, c.Qb, c.Kb, c.Vt, 1024, 256);
  qkv_scatter_kernel<<<dim3(4,24),  256, 0, s>>>(c.qr_t, c.tqs, c.tks, c.Qb, c.Kb, c.Vt, 256, 0);
  // attention in 4 chunks of 6 heads; PV split-K atomically into f32 O
  zerof_kernel<<<1920, 256, 0, s>>>(c.Of, (long)2*1280*768);
  for (int ch = 0; ch < 4; ch++){
    const bf16* Qc = c.Qb + (size_t)ch * 6 * 1280 * 64;
    const bf16* Kc = c.Kb + (size_t)ch * 6 * 1280 * 64;
    const bf16* Vc = c.Vt + (size_t)ch * 6 * 1280 * 64;
    float* Ocf = c.Of + (size_t)(ch >> 1) * 1280 * 768 + (size_t)(ch & 1) * 6 * 64;
    gemm_kernel<false,false,false,0,false,false><<<dim3(10,10,6), 256, 0, s>>>(
        Qc, nullptr, (const void*)Kc, nullptr, c.S, 1280, 1280, 64,
        (long)1280*64, (long)1280*64, 1, (long)1280*1280, 0, 1280, 0.125f, 1,
        nullptr, nullptr, nullptr);
    softmax_kernel<<<6*1280, 256, 0, s>>>(c.S, c.P);
    gemm_kernel<false,false,false,2,false,false><<<dim3(1,10,12), 256, 0, s>>>(
        c.P, nullptr, (const void*)Vc, nullptr, Ocf, 1280, 64, 1280,
        (long)1280*1280, (long)64*1280, 1, 64, 0, 768, 1.f, 2,
        nullptr, nullptr, nullptr);
  }
  f2b_kernel<<<962, 256, 0, s>>>(c.Of, c.O, (long)2*1280*768);
  // proj GEMMs (split-K=2, atomic f32)
  zerof_kernel<<<1536, 256, 0, s>>>(c.pj_i, (long)2048*768);
  zerof_kernel<<<384,  256, 0, s>>>(c.pj_t, (long)512*768);
  gemm_kernel<BF,false,false,2,true,false><<<dim3(6,8,4), 256, 0, s>>>(
      c.O + (long)256*768, nullptr, c.ipw, c.ipb, c.pj_i, 1024, 768, 768,
      (long)1280*768, 0, 1, (long)1024*768, 0, 768, 1.f, 2, nullptr, nullptr, nullptr);
  gemm_kernel<BF,false,false,2,true,false><<<dim3(6,2,4), 256, 0, s>>>(
      c.O, nullptr, c.tpw, c.tpb, c.pj_t, 256, 768, 768,
      (long)1280*768, 0, 1, (long)256*768, 0, 768, 1.f, 2, nullptr, nullptr, nullptr);
  resid_ln_mod_kernel<<<2048, 256, 0, s>>>(c.img, c.pj_i, c.mod_i, c.h_i, c.x2_i, c.x2f_i, 1024);
  resid_ln_mod_kernel<<<512,  256, 0, s>>>(c.txt, c.pj_t, c.mod_t, c.h_t, c.x2_t, c.x2f_t, 256);
  // routers
  router_kernel<<<512, 256, 0, s>>>(c.x2f_i, c.igw, c.tkw_i, c.tki_i, c.cnt_i, 2048);
  router_kernel<<<128, 256, 0, s>>>(c.x2f_t, c.tgw, c.tkw_t, c.tki_t, c.cnt_t, 512);
  offsets_kernel<<<1, 1, 0, s>>>(c.cnt_i, c.ofs_i, c.cur_i);
  offsets_kernel<<<1, 1, 0, s>>>(c.cnt_t, c.ofs_t, c.cur_t);
  scatter_kernel<<<16, 256, 0, s>>>(c.tki_i, c.ofs_i, c.cur_i, c.rows_i, c.tpos_i, 2048);
  scatter_kernel<<<4,  256, 0, s>>>(c.tki_t, c.ofs_t, c.cur_t, c.rows_t, c.tpos_t, 512);
  // ---- img MoE ----
  gemm_kernel<BF,true,true,1,false,false><<<dim3(24,16,8), 256, 0, s>>>(
      c.x2_i, nullptr, c.ieg, nullptr, c.g_i, 2048, 3072, 768, 0, (long)3072*768,
      1, 0, 0, 3072, 1.f, 1, c.rows_i, c.ofs_i, c.cnt_i);
  gemm_kernel<BF,true,true,1,false,false><<<dim3(24,16,8), 256, 0, s>>>(
      c.x2_i, nullptr, c.ieu, nullptr, c.u_i, 2048, 3072, 768, 0, (long)3072*768,
      1, 0, 0, 3072, 1.f, 1, c.rows_i, c.ofs_i, c.cnt_i);
  zerof_kernel<<<3072, 256, 0, s>>>(c.ye_i, (long)4096*768);
  gemm_kernel<BF,true,false,2,false,true><<<dim3(6,16,16), 256, 0, s>>>(
      c.g_i, c.u_i, c.ied, nullptr, c.ye_i, 2048, 768, 3072, 0, (long)768*3072,
      1, 0, 0, 768, 1.f, 2, nullptr, c.ofs_i, c.cnt_i);
  gemm_kernel<BF,false,false,1,false,false><<<dim3(12,16,1), 256, 0, s>>>(
      c.x2_i, nullptr, c.isg, nullptr, c.gs_i, 2048, 1536, 768, 0, 0,
      1, 0, 0, 1536, 1.f, 1, nullptr, nullptr, nullptr);
  gemm_kernel<BF,false,false,1,false,false><<<dim3(12,16,1), 256, 0, s>>>(
      c.x2_i, nullptr, c.isu, nullptr, c.us_i, 2048, 1536, 768, 0, 0,
      1, 0, 0, 1536, 1.f, 1, nullptr, nullptr, nullptr);
  zerof_kernel<<<1536, 256, 0, s>>>(c.ys_i, (long)2048*768);
  gemm_kernel<BF,false,false,2,false,true><<<dim3(6,16,2), 256, 0, s>>>(
      c.gs_i, c.us_i, c.isd, nullptr, c.ys_i, 2048, 768, 1536, 0, 0,
      1, 0, 0, 768, 1.f, 2, nullptr, nullptr, nullptr);
  combine_kernel<<<2048, 256, 0, s>>>(c.h_i, c.mod_i, c.tkw_i, c.tpos_i, c.ye_i, c.ys_i, c.out_img, 1024);
  // ---- txt MoE ----
  gemm_kernel<BF,true,true,1,false,false><<<dim3(24,4,8), 256, 0, s>>>(
      c.x2_t, nullptr, c.teg, nullptr, c.g_t, 512, 3072, 768, 0, (long)3072*768,
      1, 0, 0, 3072, 1.f, 1, c.rows_t, c.ofs_t, c.cnt_t);
  gemm_kernel<BF,true,true,1,false,false><<<dim3(24,4,8), 256, 0, s>>>(
      c.x2_t, nullptr, c.teu, nullptr, c.u_t, 512, 3072, 768, 0, (long)3072*768,
      1, 0, 0, 3072, 1.f, 1, c.rows_t, c.ofs_t, c.cnt_t);
  zerof_kernel<<<768, 256, 0, s>>>(c.ye_t, (long)1024*768);
  gemm_kernel<BF,true,false,2,false,true><<<dim3(6,4,32), 256, 0, s>>>(
      c.g_t, c.u_t, c.ted, nullptr, c.ye_t, 512, 768, 3072, 0, (long)768*3072,
      1, 0, 0, 768, 1.f, 4, nullptr, c.ofs_t, c.cnt_t);
  gemm_kernel<BF,false,false,1,false,false><<<dim3(12,4,1), 256, 0, s>>>(
      c.x2_t, nullptr, c.tsg, nullptr, c.gs_t, 512, 1536, 768, 0, 0,
      1, 0, 0, 1536, 1.f, 1, nullptr, nullptr, nullptr);
  gemm_kernel<BF,false,false,1,false,false><<<dim3(12,4,1), 256, 0, s>>>(
      c.x2_t, nullptr, c.tsu, nullptr, c.us_t, 512, 1536, 768, 0, 0,
      1, 0, 0, 1536, 1.f, 1, nullptr, nullptr, nullptr);
  zerof_kernel<<<384, 256, 0, s>>>(c.ys_t, (long)512*768);
  gemm_kernel<BF,false,false,2,false,true><<<dim3(6,4,4), 256, 0, s>>>(
      c.gs_t, c.us_t, c.tsd, nullptr, c.ys_t, 512, 768, 1536, 0, 0,
      1, 0, 0, 768, 1.f, 4, nullptr, nullptr, nullptr);
  combine_kernel<<<512, 256, 0, s>>>(c.h_t, c.mod_t, c.tkw_t, c.tpos_t, c.ye_t, c.ys_t, c.out_txt, 256);
}

extern "C" void kernel_launch(void* const* d_in, const int* in_sizes, int n_in,
                              void* d_out, int out_size, void* d_ws, size_t ws_size,
                              hipStream_t stream){
  (void)in_sizes; (void)n_in; (void)out_size;
  const float* fin[33];
  for (int i = 0; i < 33; i++) fin[i] = (const float*)d_in[i];

  char* ws = (char*)d_ws;
  size_t off = 0, peak = 0;
  auto alloc = [&](size_t n)->char*{
    off = (off + 255) & ~(size_t)255;
    char* p = ws + off; off += n;
    if (off > peak) peak = off;
    return p;
  };

  Ctx c{};
  c.img=fin[0]; c.txt=fin[1]; c.vec=fin[2]; c.imw=fin[3]; c.imb=fin[4];
  c.tmw=fin[5]; c.tmb=fin[6]; c.iqkvb=fin[8]; c.ipb=fin[10];
  c.tqkvb=fin[12]; c.tpb=fin[14]; c.iqs=fin[15]; c.iks=fin[16];
  c.tqs=fin[17]; c.tks=fin[18]; c.igw=fin[19]; c.tgw=fin[26];
  c.out_img = (float*)d_out;
  c.out_txt = (float*)d_out + (long)2*1024*768;

  // ---- layout builder ----
  bf16 *wq_i=nullptr,*wq_t=nullptr,*wp_i=nullptr,*wp_t=nullptr;
  bf16 *weg=nullptr,*weu=nullptr,*wed=nullptr,*wtg=nullptr,*wtu=nullptr,*wtd=nullptr;
  bf16 *wsg=nullptr,*wsu=nullptr,*wsd=nullptr,*wtsg=nullptr,*wtsu=nullptr,*wtsd=nullptr;
  auto build = [&](bool W){
    off = 0; peak = 0;
    // persistent
    c.mod_i=(float*)alloc(2*4608*4);  c.mod_t=(float*)alloc(2*4608*4);
    c.h_i  =(float*)alloc((size_t)2048*768*4); c.h_t=(float*)alloc((size_t)512*768*4);
    c.x2_i =(bf16*)alloc((size_t)2048*768*2);  c.x2_t=(bf16*)alloc((size_t)512*768*2);
    c.x2f_i=(float*)alloc((size_t)2048*768*4); c.x2f_t=(float*)alloc((size_t)512*768*4);
    c.tkw_i=(float*)alloc(2048*2*4); c.tki_i=(int*)alloc(2048*2*4);
    c.cnt_i=(int*)alloc(8*4); c.ofs_i=(int*)alloc(8*4); c.cur_i=(int*)alloc(8*4);
    c.rows_i=(int*)alloc(4096*4); c.tpos_i=(int*)alloc(4096*4);
    c.tkw_t=(float*)alloc(512*2*4); c.tki_t=(int*)alloc(512*2*4);
    c.cnt_t=(int*)alloc(8*4); c.ofs_t=(int*)alloc(8*4); c.cur_t=(int*)alloc(8*4);
    c.rows_t=(int*)alloc(1024*4); c.tpos_t=(int*)alloc(1024*4);
    if (W){
      const size_t EB = (size_t)8*3072*768*2;
      weg=(bf16*)alloc(EB); weu=(bf16*)alloc(EB); wed=(bf16*)alloc(EB);
      wtg=(bf16*)alloc(EB); wtu=(bf16*)alloc(EB); wtd=(bf16*)alloc(EB);
      wq_i=(bf16*)alloc((size_t)2304*768*2); wq_t=(bf16*)alloc((size_t)2304*768*2);
      wp_i=(bf16*)alloc((size_t)768*768*2);  wp_t=(bf16*)alloc((size_t)768*768*2);
      wsg=(bf16*)alloc((size_t)1536*768*2);  wsu=(bf16*)alloc((size_t)1536*768*2);
      wsd=(bf16*)alloc((size_t)768*1536*2);
      wtsg=(bf16*)alloc((size_t)1536*768*2); wtsu=(bf16*)alloc((size_t)1536*768*2);
      wtsd=(bf16*)alloc((size_t)768*1536*2);
    }
    size_t arena = (off + 255) & ~(size_t)255;
    // phase A region1
    off = arena;
    c.Qb=(bf16*)alloc((size_t)24*1280*64*2);
    c.Kb=(bf16*)alloc((size_t)24*1280*64*2);
    c.Vt=(bf16*)alloc((size_t)24*1280*64*2);
    c.O =(bf16*)alloc((size_t)2*1280*768*2);
    c.Of=(float*)alloc((size_t)2*1280*768*4);
    c.pj_i=(float*)alloc((size_t)2048*768*4);
    c.pj_t=(float*)alloc((size_t)512*768*4);
    size_t sub = (off + 255) & ~(size_t)255;
    // region2a: xm/qr (dead after scatter)
    c.xm_i=(bf16*)alloc((size_t)2048*768*2); c.xm_t=(bf16*)alloc((size_t)512*768*2);
    c.qr_i=(bf16*)alloc((size_t)2048*2304*2); c.qr_t=(bf16*)alloc((size_t)512*2304*2);
    // region2b: S/P overlays 2a
    off = sub;
    c.S=(float*)alloc((size_t)6*1280*1280*4);
    c.P=(bf16*)alloc((size_t)6*1280*1280*2);
    // phase B img overlays phase A
    off = arena;
    c.g_i=(bf16*)alloc((size_t)4096*3072*2);
    c.u_i=(bf16*)alloc((size_t)4096*3072*2);
    c.ye_i=(float*)alloc((size_t)4096*768*4);
    c.gs_i=(bf16*)alloc((size_t)2048*1536*2);
    c.us_i=(bf16*)alloc((size_t)2048*1536*2);
    c.ys_i=(float*)alloc((size_t)2048*768*4);
    // phase B txt overlays img (strictly after combine_img)
    off = arena;
    c.g_t=(bf16*)alloc((size_t)1024*3072*2);
    c.u_t=(bf16*)alloc((size_t)1024*3072*2);
    c.ye_t=(float*)alloc((size_t)1024*768*4);
    c.gs_t=(bf16*)alloc((size_t)512*1536*2);
    c.us_t=(bf16*)alloc((size_t)512*1536*2);
    c.ys_t=(float*)alloc((size_t)512*768*4);
  };

  build(true);
  bool W = (peak <= ws_size);
  if (!W) build(false);

  if (W){
    auto cv = [&](const float* src, bf16* dst, long n){
      f2b_kernel<<<(unsigned)((n/8 + 255)/256), 256, 0, stream>>>(src, dst, n);
    };
    const long EN = (long)8*3072*768;
    cv(fin[20], weg, EN); cv(fin[21], weu, EN); cv(fin[22], wed, EN);
    cv(fin[27], wtg, EN); cv(fin[28], wtu, EN); cv(fin[29], wtd, EN);
    cv(fin[7],  wq_i, (long)2304*768); cv(fin[11], wq_t, (long)2304*768);
    cv(fin[9],  wp_i, (long)768*768);  cv(fin[13], wp_t, (long)768*768);
    cv(fin[23], wsg, (long)1536*768);  cv(fin[24], wsu, (long)1536*768);
    cv(fin[25], wsd, (long)768*1536);
    cv(fin[30], wtsg,(long)1536*768);  cv(fin[31], wtsu,(long)1536*768);
    cv(fin[32], wtsd,(long)768*1536);
    c.iqkvw=wq_i; c.tqkvw=wq_t; c.ipw=wp_i; c.tpw=wp_t;
    c.ieg=weg; c.ieu=weu; c.ied=wed; c.teg=wtg; c.teu=wtu; c.ted=wtd;
    c.isg=wsg; c.isu=wsu; c.isd=wsd; c.tsg=wtsg; c.tsu=wtsu; c.tsd=wtsd;
    seq<true>(c, stream);
  } else {
    c.iqkvw=fin[7]; c.tqkvw=fin[11]; c.ipw=fin[9]; c.tpw=fin[13];
    c.ieg=fin[20]; c.ieu=fin[21]; c.ied=fin[22];
    c.teg=fin[27]; c.teu=fin[28]; c.ted=fin[29];
    c.isg=fin[23]; c.isu=fin[24]; c.isd=fin[25];
    c.tsg=fin[30]; c.tsu=fin[31]; c.tsd=fin[32];
    seq<false>(c, stream);
  }
}